// Round 1
// baseline (33535.190 us; speedup 1.0000x reference)
//
#include <hip/hip_runtime.h>
#include <math.h>

// Problem sizes (fixed by the reference)
#define SEQ 4096
#define IND 2048
#define HID 2048
#define G3  (3 * HID)   // 6144 rows of w_ih / w_hh

// Persistent scan kernel geometry
#define NWG     256     // one workgroup per CU — all co-resident
#define TPB     768     // 12 waves
#define HPW     8       // h-indices owned per WG  (256*8 = 2048)
#define ROWS    24      // 3 gates * 8 h-indices
#define LDSROWS 18      // rows kept resident in LDS (147 KB)
// remaining 6 rows streamed from global (L2-resident: 32 WG/XCD * 48KB = 1.5MB)

// Workspace layout (bytes)
#define WS_CNT 0        // barrier counter (zeroed each launch)
#define WS_H   1024     // h double buffer: 2 * 2048 floats
#define WS_H1  20480    // MLP intermediate: 2048 floats
#define WS_GI  32768    // gi_all: 4096*6144 floats = 100.66 MB

__device__ __forceinline__ int grow_of(int hbase, int r) {
    // local row r in [0,24): gate = r>>3 (r,z,n), lane = r&7
    return ((r >> 3) << 11) + hbase + (r & 7);   // gate*2048 + hbase + lane
}

// ---------------------------------------------------------------------------
// Kernel 1: gi_all = x @ w_ih^T + b_ih   (M=4096, N=6144, K=2048, fp32)
// Plain 64x64x16 LDS-tiled SGEMM, 4x4 per thread.
// ---------------------------------------------------------------------------
__global__ __launch_bounds__(256) void gi_gemm(const float* __restrict__ x,
                                               const float* __restrict__ w,
                                               const float* __restrict__ bih,
                                               float* __restrict__ gi) {
    constexpr int BM = 64, BN = 64, BK = 16, PAD = 4;
    __shared__ __align__(16) float As[BK][BM + PAD];   // stride 68 floats (16B-aligned rows)
    __shared__ __align__(16) float Bs[BK][BN + PAD];

    const int tid = threadIdx.x;
    const int m0 = blockIdx.x * BM;         // timestep dim
    const int n0 = blockIdx.y * BN;         // gate-row dim
    const int tx = tid & 15, ty = tid >> 4; // 16x16 thread grid, 4x4 micro-tile
    const int lm = tid >> 2;                // 0..63 : row within tile for loads
    const int lk = (tid & 3) << 2;          // 0,4,8,12 : k-offset for float4 load

    const float* xp = x + (size_t)(m0 + lm) * IND + lk;
    const float* wp = w + (size_t)(n0 + lm) * IND + lk;

    float c[4][4] = {};

    for (int k0 = 0; k0 < IND; k0 += BK) {
        const float4 av = *(const float4*)(xp + k0);
        const float4 bv = *(const float4*)(wp + k0);
        __syncthreads();
        As[lk + 0][lm] = av.x; As[lk + 1][lm] = av.y;
        As[lk + 2][lm] = av.z; As[lk + 3][lm] = av.w;
        Bs[lk + 0][lm] = bv.x; Bs[lk + 1][lm] = bv.y;
        Bs[lk + 2][lm] = bv.z; Bs[lk + 3][lm] = bv.w;
        __syncthreads();
#pragma unroll
        for (int k = 0; k < BK; ++k) {
            const float4 a  = *(const float4*)&As[k][ty << 2];
            const float4 bb = *(const float4*)&Bs[k][tx << 2];
            const float ar[4] = {a.x, a.y, a.z, a.w};
            const float br[4] = {bb.x, bb.y, bb.z, bb.w};
#pragma unroll
            for (int i = 0; i < 4; ++i)
#pragma unroll
                for (int j = 0; j < 4; ++j) c[i][j] += ar[i] * br[j];
        }
    }

    const int nb = n0 + (tx << 2);
    const float4 bias = *(const float4*)(bih + nb);
    const float bres[4] = {bias.x, bias.y, bias.z, bias.w};
#pragma unroll
    for (int i = 0; i < 4; ++i) {
        const int m = m0 + (ty << 2) + i;
        float4 o;
        o.x = c[i][0] + bres[0]; o.y = c[i][1] + bres[1];
        o.z = c[i][2] + bres[2]; o.w = c[i][3] + bres[3];
        *(float4*)(gi + (size_t)m * G3 + nb) = o;
    }
}

// ---------------------------------------------------------------------------
// Kernel 2: persistent GRU scan. 256 WGs (1/CU) x 768 threads.
// w_hh slice resident in LDS (18 rows fp32) + 6 rows streamed from L2.
// h exchanged through agent-scope coherent loads/stores; device-wide
// barrier = monotonic counter (release add + relaxed spin). No L2
// invalidates per step, so cached weights/gi stay hot.
// ---------------------------------------------------------------------------
__global__ __launch_bounds__(TPB, 3) void gru_scan(const float* __restrict__ whh,
                                                   const float* __restrict__ bhh,
                                                   const float* __restrict__ gi,
                                                   float* hbuf,
                                                   unsigned* cnt) {
    __shared__ __align__(16) float wl[LDSROWS][HID];   // 147456 B
    __shared__ __align__(16) float hl[HID];            // 8192 B
    __shared__ float ghs[ROWS];
    __shared__ float gis[ROWS];
    __shared__ float bs[ROWS];

    const int tid = threadIdx.x;
    const int hbase = blockIdx.x * HPW;

    // ---- one-time: stage 18 w_hh rows into LDS, biases into LDS ----
    if (tid < ROWS) bs[tid] = bhh[grow_of(hbase, tid)];
    for (int f = tid; f < LDSROWS * (HID / 4); f += TPB) {
        const int r = f >> 9;              // /512
        const int c4 = f & 511;
        const float4 v = *(const float4*)(whh + (size_t)grow_of(hbase, r) * HID + (c4 << 2));
        *(float4*)&wl[r][c4 << 2] = v;
    }
    __syncthreads();

    const int wv = tid >> 6;      // wave 0..11
    const int ln = tid & 63;
    const int r0 = wv << 1;       // two local rows per wave

    // pointers for the streamed rows (waves 9..11 -> local rows 18..23)
    const float* sp0 = whh + (size_t)grow_of(hbase, r0 < ROWS ? r0 : 0) * HID;
    const float* sp1 = whh + (size_t)grow_of(hbase, (r0 + 1) < ROWS ? r0 + 1 : 0) * HID;

    for (int t = 0; t < SEQ; ++t) {
        const float* hsrc = hbuf + ((t & 1) << 11);
        float* hdst = hbuf + (((t + 1) & 1) << 11);

        // ---- fetch h (coherent, from L3) into LDS; fetch this step's gi ----
        for (int i = tid; i < HID; i += TPB)
            hl[i] = __hip_atomic_load(hsrc + i, __ATOMIC_RELAXED, __HIP_MEMORY_SCOPE_AGENT);
        if (tid < ROWS)
            gis[tid] = gi[(size_t)t * G3 + grow_of(hbase, tid)];
        __syncthreads();

        // ---- GEMV: each wave reduces its two rows over K=2048 ----
        float acc0 = 0.f, acc1 = 0.f;
        if (r0 < LDSROWS) {
#pragma unroll
            for (int i = 0; i < 8; ++i) {
                const int o = ((i << 6) + ln) << 2;
                const float4 h4 = *(const float4*)&hl[o];
                const float4 w0 = *(const float4*)&wl[r0][o];
                const float4 w1 = *(const float4*)&wl[r0 + 1][o];
                acc0 += w0.x * h4.x + w0.y * h4.y + w0.z * h4.z + w0.w * h4.w;
                acc1 += w1.x * h4.x + w1.y * h4.y + w1.z * h4.z + w1.w * h4.w;
            }
        } else {
#pragma unroll
            for (int i = 0; i < 8; ++i) {
                const int o = ((i << 6) + ln) << 2;
                const float4 h4 = *(const float4*)&hl[o];
                const float4 w0 = *(const float4*)(sp0 + o);
                const float4 w1 = *(const float4*)(sp1 + o);
                acc0 += w0.x * h4.x + w0.y * h4.y + w0.z * h4.z + w0.w * h4.w;
                acc1 += w1.x * h4.x + w1.y * h4.y + w1.z * h4.z + w1.w * h4.w;
            }
        }
#pragma unroll
        for (int d = 1; d < 64; d <<= 1) {
            acc0 += __shfl_xor(acc0, d);
            acc1 += __shfl_xor(acc1, d);
        }
        if (ln == 0) {
            ghs[r0] = acc0 + bs[r0];
            ghs[r0 + 1] = acc1 + bs[r0 + 1];
        }
        __syncthreads();

        // ---- gates + h_new for this WG's 8 indices ----
        if (tid < HPW) {
            const float ir = gis[tid], iz = gis[8 + tid], in_ = gis[16 + tid];
            const float hr = ghs[tid], hz = ghs[8 + tid], hn = ghs[16 + tid];
            const float hprev = hl[hbase + tid];
            const float rg = 1.f / (1.f + __expf(-(ir + hr)));
            const float zg = 1.f / (1.f + __expf(-(iz + hz)));
            const float ng = tanhf(in_ + rg * hn);
            const float hnew = (1.f - zg) * ng + zg * hprev;
            __hip_atomic_store(hdst + hbase + tid, hnew,
                               __ATOMIC_RELAXED, __HIP_MEMORY_SCOPE_AGENT);
        }
        // s_barrier is preceded by s_waitcnt vmcnt(0): the 8 stores above have
        // reached the coherence point before any thread passes this barrier.
        __syncthreads();

        // ---- device-wide barrier (skip after the last step) ----
        if (t < SEQ - 1) {
            if (tid == 0) {
                __hip_atomic_fetch_add(cnt, 1u, __ATOMIC_RELEASE, __HIP_MEMORY_SCOPE_AGENT);
                const unsigned tgt = (unsigned)(t + 1) * NWG;
                while (__hip_atomic_load(cnt, __ATOMIC_RELAXED, __HIP_MEMORY_SCOPE_AGENT) < tgt) {
                }
                __builtin_amdgcn_sched_barrier(0);
            }
            __syncthreads();
        }
    }
}

// ---------------------------------------------------------------------------
// Kernel 3: GEMV  out[row] = act( b[row] + dot(h, w[row]) )
// one wave per output row; 4 rows per WG.
// ---------------------------------------------------------------------------
__global__ __launch_bounds__(256) void mlp_gemv(const float* __restrict__ h,
                                                const float* __restrict__ w,
                                                const float* __restrict__ b,
                                                float* __restrict__ out,
                                                int relu) {
    __shared__ __align__(16) float hs[HID];
    for (int i = threadIdx.x; i < HID; i += 256) hs[i] = h[i];
    __syncthreads();
    const int wv = threadIdx.x >> 6, ln = threadIdx.x & 63;
    const int row = (blockIdx.x << 2) + wv;
    const float* wp = w + (size_t)row * HID;
    float acc = 0.f;
#pragma unroll
    for (int i = 0; i < 8; ++i) {
        const int o = ((i << 6) + ln) << 2;
        const float4 w4 = *(const float4*)(wp + o);
        const float4 h4 = *(const float4*)&hs[o];
        acc += w4.x * h4.x + w4.y * h4.y + w4.z * h4.z + w4.w * h4.w;
    }
#pragma unroll
    for (int d = 1; d < 64; d <<= 1) acc += __shfl_xor(acc, d);
    if (ln == 0) {
        float v = acc + (b ? b[row] : 0.f);
        if (relu) v = fmaxf(v, 0.f);
        out[row] = v;
    }
}

// ---------------------------------------------------------------------------
extern "C" void kernel_launch(void* const* d_in, const int* in_sizes, int n_in,
                              void* d_out, int out_size, void* d_ws, size_t ws_size,
                              hipStream_t stream) {
    const float* x   = (const float*)d_in[0];
    const float* h0  = (const float*)d_in[1];
    const float* wih = (const float*)d_in[2];
    const float* whh = (const float*)d_in[3];
    const float* bih = (const float*)d_in[4];
    const float* bhh = (const float*)d_in[5];
    const float* fw1 = (const float*)d_in[6];
    const float* fb1 = (const float*)d_in[7];
    const float* fw2 = (const float*)d_in[8];
    float* out = (float*)d_out;

    char* ws = (char*)d_ws;
    unsigned* cnt = (unsigned*)(ws + WS_CNT);
    float* hbuf   = (float*)(ws + WS_H);
    float* h1buf  = (float*)(ws + WS_H1);
    float* gibuf  = (float*)(ws + WS_GI);

    // barrier counter must start at 0 (ws is poisoned 0xAA before every call)
    hipMemsetAsync(cnt, 0, 128, stream);
    // h double-buffer slot 0 = h0
    hipMemcpyAsync(hbuf, h0, HID * sizeof(float), hipMemcpyDeviceToDevice, stream);

    // 1) input projections for all timesteps
    dim3 gg(SEQ / 64, G3 / 64);
    gi_gemm<<<gg, 256, 0, stream>>>(x, wih, bih, gibuf);

    // 2) persistent sequential scan (one WG per CU)
    gru_scan<<<NWG, TPB, 0, stream>>>(whh, bhh, gibuf, hbuf, cnt);

    // 3) MLP head: h1 = relu(h @ fc_w1^T + fc_b1); out = h1 @ fc_w2^T
    mlp_gemv<<<HID / 4, 256, 0, stream>>>(hbuf, fw1, fb1, h1buf, 1);
    mlp_gemv<<<HID / 4, 256, 0, stream>>>(h1buf, fw2, nullptr, out, 0);
}

// Round 2
// 31007.941 us; speedup vs baseline: 1.0815x; 1.0815x over previous
//
#include <hip/hip_runtime.h>
#include <math.h>

// Problem sizes (fixed by the reference)
#define SEQ 4096
#define IND 2048
#define HID 2048
#define G3  (3 * HID)

// Persistent scan kernel geometry
#define NWG  256    // one workgroup per CU
#define TPB  768    // 12 waves: 3 row-groups (gates) x 4 col-groups
#define HPW  8      // h-indices owned per WG
#define ROWS 24     // 3 gates * 8

// Workspace layout (bytes)
#define WS_FLAGS 0      // 256 u32 arrival flags (memset 0 each launch)
#define WS_H     1024   // h double buffer: 2 * 2048 floats
#define WS_H1    20480  // MLP intermediate
#define WS_GI    32768  // gi_all: 4096*6144 floats

__device__ __forceinline__ int grow_of(int hbase, int r) {
    return ((r >> 3) << 11) + hbase + (r & 7);   // gate*2048 + hbase + idx
}

__device__ __forceinline__ float sigm(float x) { return 1.f / (1.f + __expf(-x)); }
__device__ __forceinline__ float tanh_fast(float x) {
    const float e = __expf(2.f * x);             // inf/0 saturate correctly
    return 1.f - 2.f / (e + 1.f);
}

// ---------------------------------------------------------------------------
// Kernel 1: gi_all = x @ w_ih^T + b_ih   (unchanged from r1; ~1.2 ms measured)
// ---------------------------------------------------------------------------
__global__ __launch_bounds__(256) void gi_gemm(const float* __restrict__ x,
                                               const float* __restrict__ w,
                                               const float* __restrict__ bih,
                                               float* __restrict__ gi) {
    constexpr int BM = 64, BN = 64, BK = 16, PAD = 4;
    __shared__ __align__(16) float As[BK][BM + PAD];
    __shared__ __align__(16) float Bs[BK][BN + PAD];

    const int tid = threadIdx.x;
    const int m0 = blockIdx.x * BM;
    const int n0 = blockIdx.y * BN;
    const int tx = tid & 15, ty = tid >> 4;
    const int lm = tid >> 2;
    const int lk = (tid & 3) << 2;

    const float* xp = x + (size_t)(m0 + lm) * IND + lk;
    const float* wp = w + (size_t)(n0 + lm) * IND + lk;

    float c[4][4] = {};

    for (int k0 = 0; k0 < IND; k0 += BK) {
        const float4 av = *(const float4*)(xp + k0);
        const float4 bv = *(const float4*)(wp + k0);
        __syncthreads();
        As[lk + 0][lm] = av.x; As[lk + 1][lm] = av.y;
        As[lk + 2][lm] = av.z; As[lk + 3][lm] = av.w;
        Bs[lk + 0][lm] = bv.x; Bs[lk + 1][lm] = bv.y;
        Bs[lk + 2][lm] = bv.z; Bs[lk + 3][lm] = bv.w;
        __syncthreads();
#pragma unroll
        for (int k = 0; k < BK; ++k) {
            const float4 a  = *(const float4*)&As[k][ty << 2];
            const float4 bb = *(const float4*)&Bs[k][tx << 2];
            const float ar[4] = {a.x, a.y, a.z, a.w};
            const float br[4] = {bb.x, bb.y, bb.z, bb.w};
#pragma unroll
            for (int i = 0; i < 4; ++i)
#pragma unroll
                for (int j = 0; j < 4; ++j) c[i][j] += ar[i] * br[j];
        }
    }

    const int nb = n0 + (tx << 2);
    const float4 bias = *(const float4*)(bih + nb);
    const float bres[4] = {bias.x, bias.y, bias.z, bias.w};
#pragma unroll
    for (int i = 0; i < 4; ++i) {
        const int m = m0 + (ty << 2) + i;
        float4 o;
        o.x = c[i][0] + bres[0]; o.y = c[i][1] + bres[1];
        o.z = c[i][2] + bres[2]; o.w = c[i][3] + bres[3];
        *(float4*)(gi + (size_t)m * G3 + nb) = o;
    }
}

// ---------------------------------------------------------------------------
// Kernel 2: persistent GRU scan, w_hh in REGISTERS.
//   wave wv = rg*4+cg: rows [rg*8, rg*8+8) x cols [cg*512, cg*512+512)
//   lane  = r*8+c: row rg*8+r, col float4s {cg*128 + 8k + c : k=0..15}
//   -> 64 w-VGPRs/lane; hl reads are 8-lane-broadcast, bank-conflict-free.
// Sync: per-WG flag slot (release store), wave0 polls all 256 at step start.
// ---------------------------------------------------------------------------
__global__ __launch_bounds__(TPB, 3) void gru_scan(const float* __restrict__ whh,
                                                   const float* __restrict__ bhh,
                                                   const float* __restrict__ gi,
                                                   float* hbuf,
                                                   unsigned* flags) {
    // LDS: hl (8KB) + partials; padded to ~86KB to keep 1 WG/CU.
    __shared__ __align__(16) float hl[HID];
    __shared__ float part[ROWS][4];
    __shared__ float lds_pad[19968];   // 79.9KB pad (dummy use below keeps it)

    const int tid = threadIdx.x;
    const int wg  = blockIdx.x;
    const int hbase = wg * HPW;
    if ((int)blockIdx.y < 0) lds_pad[tid] = 0.f;   // never true; forces allocation

    const int wv = tid >> 6, ln = tid & 63;
    const int rg = wv >> 2, cg = wv & 3;   // row-group (=gate), col-group
    const int r  = ln >> 3, c  = ln & 7;
    const int lrow = rg * 8 + r;
    const int grow = (rg << 11) + hbase + r;       // global w_hh row

    // ---- one-time: w slice -> registers; bias for (c==0, cg==0) lanes ----
    const float* wrow = whh + (size_t)grow * HID;
    float4 w4[16];
#pragma unroll
    for (int k = 0; k < 16; ++k)
        w4[k] = *(const float4*)(wrow + (((cg << 7) + (k << 3) + c) << 2));
    const float breg = (c == 0 && cg == 0) ? bhh[grow] : 0.f;

    // gi prefetch register (wave 0, tid<24)
    float gcur = 0.f;
    if (tid < ROWS) gcur = gi[grow_of(hbase, tid)];

    const float4* hl4 = (const float4*)hl;

    for (int t = 0; t < SEQ; ++t) {
        const float* hsrc = hbuf + ((t & 1) << 11);
        float* hdst = hbuf + (((t + 1) & 1) << 11);

        // ---- wait for h(t): all WGs' flags >= t ----
        if (t > 0 && tid < 64) {
            const unsigned* fp = flags + (tid << 2);
            const unsigned tgt = (unsigned)t;
            for (;;) {
                const unsigned f0 = __hip_atomic_load(fp + 0, __ATOMIC_RELAXED, __HIP_MEMORY_SCOPE_AGENT);
                const unsigned f1 = __hip_atomic_load(fp + 1, __ATOMIC_RELAXED, __HIP_MEMORY_SCOPE_AGENT);
                const unsigned f2 = __hip_atomic_load(fp + 2, __ATOMIC_RELAXED, __HIP_MEMORY_SCOPE_AGENT);
                const unsigned f3 = __hip_atomic_load(fp + 3, __ATOMIC_RELAXED, __HIP_MEMORY_SCOPE_AGENT);
                if (__all(f0 >= tgt && f1 >= tgt && f2 >= tgt && f3 >= tgt)) break;
                __builtin_amdgcn_s_sleep(1);
            }
        }
        __syncthreads();   // B1: safe to overwrite hl

        // ---- h(t) -> LDS (all loads issued before any wait) + gi(t+1) prefetch ----
        const float v0 = __hip_atomic_load(hsrc + tid,       __ATOMIC_RELAXED, __HIP_MEMORY_SCOPE_AGENT);
        const float v1 = __hip_atomic_load(hsrc + tid + 768, __ATOMIC_RELAXED, __HIP_MEMORY_SCOPE_AGENT);
        float v2 = 0.f;
        if (tid < 512)
            v2 = __hip_atomic_load(hsrc + tid + 1536, __ATOMIC_RELAXED, __HIP_MEMORY_SCOPE_AGENT);
        float gnxt = 0.f;
        if (t + 1 < SEQ && tid < ROWS)
            gnxt = gi[(size_t)(t + 1) * G3 + grow_of(hbase, tid)];
        hl[tid] = v0;
        hl[tid + 768] = v1;
        if (tid < 512) hl[tid + 1536] = v2;
        __syncthreads();   // B2: hl ready

        // ---- GEMV from registers: acc over this lane's 64 cols ----
        float4 acc4 = {0.f, 0.f, 0.f, 0.f};
#pragma unroll
        for (int k = 0; k < 16; ++k) {
            const float4 h4 = hl4[(cg << 7) + (k << 3) + c];
            acc4.x += w4[k].x * h4.x; acc4.y += w4[k].y * h4.y;
            acc4.z += w4[k].z * h4.z; acc4.w += w4[k].w * h4.w;
        }
        float acc = (acc4.x + acc4.y) + (acc4.z + acc4.w) + breg;
        acc += __shfl_xor(acc, 1);
        acc += __shfl_xor(acc, 2);
        acc += __shfl_xor(acc, 4);
        if (c == 0) part[lrow][cg] = acc;
        __syncthreads();   // B3: partials ready

        // ---- gates (wave 0) ----
        const float izs = __shfl(gcur, tid + 8);    // convergent in wave 0
        const float ins = __shfl(gcur, tid + 16);
        if (tid < HPW) {
            const float hr = part[tid][0] + part[tid][1] + part[tid][2] + part[tid][3];
            const float hz = part[8 + tid][0] + part[8 + tid][1] + part[8 + tid][2] + part[8 + tid][3];
            const float hn = part[16 + tid][0] + part[16 + tid][1] + part[16 + tid][2] + part[16 + tid][3];
            const float hprev = hl[hbase + tid];
            const float rg_ = sigm(gcur + hr);
            const float zg_ = sigm(izs + hz);
            const float ng_ = tanh_fast(ins + rg_ * hn);
            const float hnew = (1.f - zg_) * ng_ + zg_ * hprev;
            __hip_atomic_store(hdst + hbase + tid, hnew,
                               __ATOMIC_RELAXED, __HIP_MEMORY_SCOPE_AGENT);
        }
        if (tid == 0)   // release: h stores (same wave) drain before flag visible
            __hip_atomic_store(flags + wg, (unsigned)(t + 1),
                               __ATOMIC_RELEASE, __HIP_MEMORY_SCOPE_AGENT);
        gcur = gnxt;
    }
}

// ---------------------------------------------------------------------------
// Kernel 3: GEMV  out[row] = act( b[row] + dot(h, w[row]) )
// ---------------------------------------------------------------------------
__global__ __launch_bounds__(256) void mlp_gemv(const float* __restrict__ h,
                                                const float* __restrict__ w,
                                                const float* __restrict__ b,
                                                float* __restrict__ out,
                                                int relu) {
    __shared__ __align__(16) float hs[HID];
    for (int i = threadIdx.x; i < HID; i += 256) hs[i] = h[i];
    __syncthreads();
    const int wv = threadIdx.x >> 6, ln = threadIdx.x & 63;
    const int row = (blockIdx.x << 2) + wv;
    const float* wp = w + (size_t)row * HID;
    float acc = 0.f;
#pragma unroll
    for (int i = 0; i < 8; ++i) {
        const int o = ((i << 6) + ln) << 2;
        const float4 w4 = *(const float4*)(wp + o);
        const float4 h4 = *(const float4*)&hs[o];
        acc += w4.x * h4.x + w4.y * h4.y + w4.z * h4.z + w4.w * h4.w;
    }
#pragma unroll
    for (int d = 1; d < 64; d <<= 1) acc += __shfl_xor(acc, d);
    if (ln == 0) {
        float v = acc + (b ? b[row] : 0.f);
        if (relu) v = fmaxf(v, 0.f);
        out[row] = v;
    }
}

// ---------------------------------------------------------------------------
extern "C" void kernel_launch(void* const* d_in, const int* in_sizes, int n_in,
                              void* d_out, int out_size, void* d_ws, size_t ws_size,
                              hipStream_t stream) {
    const float* x   = (const float*)d_in[0];
    const float* h0  = (const float*)d_in[1];
    const float* wih = (const float*)d_in[2];
    const float* whh = (const float*)d_in[3];
    const float* bih = (const float*)d_in[4];
    const float* bhh = (const float*)d_in[5];
    const float* fw1 = (const float*)d_in[6];
    const float* fb1 = (const float*)d_in[7];
    const float* fw2 = (const float*)d_in[8];
    float* out = (float*)d_out;

    char* ws = (char*)d_ws;
    unsigned* flags = (unsigned*)(ws + WS_FLAGS);
    float* hbuf   = (float*)(ws + WS_H);
    float* h1buf  = (float*)(ws + WS_H1);
    float* gibuf  = (float*)(ws + WS_GI);

    hipMemsetAsync(flags, 0, NWG * sizeof(unsigned), stream);
    hipMemcpyAsync(hbuf, h0, HID * sizeof(float), hipMemcpyDeviceToDevice, stream);

    dim3 gg(SEQ / 64, G3 / 64);
    gi_gemm<<<gg, 256, 0, stream>>>(x, wih, bih, gibuf);

    gru_scan<<<NWG, TPB, 0, stream>>>(whh, bhh, gibuf, hbuf, flags);

    mlp_gemv<<<HID / 4, 256, 0, stream>>>(hbuf, fw1, fb1, h1buf, 1);
    mlp_gemv<<<HID / 4, 256, 0, stream>>>(h1buf, fw2, nullptr, out, 0);
}

// Round 3
// 18997.148 us; speedup vs baseline: 1.7653x; 1.6322x over previous
//
#include <hip/hip_runtime.h>
#include <math.h>
#include <stdint.h>

// Problem sizes (fixed by the reference)
#define SEQ 4096
#define IND 2048
#define HID 2048
#define G3  (3 * HID)

// Persistent scan geometry
#define NWG  256    // one workgroup per CU
#define TPB  768    // 12 waves: wave wv owns rows {2wv, 2wv+1} of the 24-row slice
#define HPW  8      // h-indices owned per WG
#define ROWS 24     // 3 gates * 8

// Workspace layout (bytes)
#define WS_REC 0        // h records: 2 slots * 2048 * 8B = 32 KB
#define WS_H   32768    // final hidden state: 2048 floats
#define WS_H1  45056    // MLP intermediate: 2048 floats
#define WS_GI  65536    // gi_all: 4096*6144 floats = 100.66 MB

__device__ __forceinline__ int grow_of(int hbase, int r) {
    return ((r >> 3) << 11) + hbase + (r & 7);   // gate*2048 + hbase + idx
}
__device__ __forceinline__ float sigm(float x) { return 1.f / (1.f + __expf(-x)); }
__device__ __forceinline__ float tanh_fast(float x) {
    const float e = __expf(2.f * x);
    return 1.f - 2.f / (e + 1.f);
}
__device__ __forceinline__ uint64_t pack_rec(float v, unsigned e) {
    union { float f; unsigned u; } c; c.f = v;
    return ((uint64_t)c.u << 32) | (uint64_t)e;
}
__device__ __forceinline__ float rec_val(uint64_t r) {
    union { unsigned u; float f; } c; c.u = (unsigned)(r >> 32);
    return c.f;
}

// ---------------------------------------------------------------------------
// Kernel 1: gi_all = x @ w_ih^T + b_ih  (unchanged; ~1.1 ms)
// ---------------------------------------------------------------------------
__global__ __launch_bounds__(256) void gi_gemm(const float* __restrict__ x,
                                               const float* __restrict__ w,
                                               const float* __restrict__ bih,
                                               float* __restrict__ gi) {
    constexpr int BM = 64, BN = 64, BK = 16, PAD = 4;
    __shared__ __align__(16) float As[BK][BM + PAD];
    __shared__ __align__(16) float Bs[BK][BN + PAD];

    const int tid = threadIdx.x;
    const int m0 = blockIdx.x * BM;
    const int n0 = blockIdx.y * BN;
    const int tx = tid & 15, ty = tid >> 4;
    const int lm = tid >> 2;
    const int lk = (tid & 3) << 2;

    const float* xp = x + (size_t)(m0 + lm) * IND + lk;
    const float* wp = w + (size_t)(n0 + lm) * IND + lk;

    float c[4][4] = {};

    for (int k0 = 0; k0 < IND; k0 += BK) {
        const float4 av = *(const float4*)(xp + k0);
        const float4 bv = *(const float4*)(wp + k0);
        __syncthreads();
        As[lk + 0][lm] = av.x; As[lk + 1][lm] = av.y;
        As[lk + 2][lm] = av.z; As[lk + 3][lm] = av.w;
        Bs[lk + 0][lm] = bv.x; Bs[lk + 1][lm] = bv.y;
        Bs[lk + 2][lm] = bv.z; Bs[lk + 3][lm] = bv.w;
        __syncthreads();
#pragma unroll
        for (int k = 0; k < BK; ++k) {
            const float4 a  = *(const float4*)&As[k][ty << 2];
            const float4 bb = *(const float4*)&Bs[k][tx << 2];
            const float ar[4] = {a.x, a.y, a.z, a.w};
            const float br[4] = {bb.x, bb.y, bb.z, bb.w};
#pragma unroll
            for (int i = 0; i < 4; ++i)
#pragma unroll
                for (int j = 0; j < 4; ++j) c[i][j] += ar[i] * br[j];
        }
    }

    const int nb = n0 + (tx << 2);
    const float4 bias = *(const float4*)(bih + nb);
    const float bres[4] = {bias.x, bias.y, bias.z, bias.w};
#pragma unroll
    for (int i = 0; i < 4; ++i) {
        const int m = m0 + (ty << 2) + i;
        float4 o;
        o.x = c[i][0] + bres[0]; o.y = c[i][1] + bres[1];
        o.z = c[i][2] + bres[2]; o.w = c[i][3] + bres[3];
        *(float4*)(gi + (size_t)m * G3 + nb) = o;
    }
}

// ---------------------------------------------------------------------------
// Kernel 2: persistent GRU scan — fused (value,epoch) 8B records.
//  - producer: ONE relaxed 8B agent atomic per h element; no fence/flag.
//  - consumer: 8 polling waves read all 2048 records (detect == load),
//    deposit into XOR-swizzled LDS, publish per-wave LDS epoch flags.
//  - GEMV: wave wv -> rows {2wv,2wv+1}; lane ln -> 32 unique cols
//    (granules 8ln..8ln+7, swizzled) -> 96 KB LDS traffic/step.
// ---------------------------------------------------------------------------
__global__ __launch_bounds__(TPB, 3) void gru_scan(const float* __restrict__ whh,
                                                   const float* __restrict__ bhh,
                                                   const float* __restrict__ gi,
                                                   const float* __restrict__ h0,
                                                   uint64_t* rec,
                                                   float* __restrict__ hout) {
    __shared__ __align__(16) float hl[HID];   // swizzled float4 granules
    __shared__ float part[ROWS];
    __shared__ unsigned lflag[8];

    const int tid = threadIdx.x;
    const int wg  = blockIdx.x;
    const int hbase = wg * HPW;
    const int wv = tid >> 6, ln = tid & 63;

    if (tid < 8) lflag[tid] = 0;

    // ---- weights for rows {2wv, 2wv+1}, lane's 8 column-granules ----
    const int lr0 = 2 * wv, lr1 = lr0 + 1;
    const int grow0 = grow_of(hbase, lr0);
    const int grow1 = grow_of(hbase, lr1);
    const float* w0p = whh + (size_t)grow0 * HID;
    const float* w1p = whh + (size_t)grow1 * HID;
    float4 wa[8], wb[8];
#pragma unroll
    for (int k = 0; k < 8; ++k) {
        wa[k] = *(const float4*)(w0p + (((ln << 3) + k) << 2));
        wb[k] = *(const float4*)(w1p + (((ln << 3) + k) << 2));
    }
    const float b0 = bhh[grow0], b1 = bhh[grow1];

    // ---- wave 0 state: gi prefetch (lanes<24), h_prev regs (lanes<8) ----
    float gcur = 0.f, hcur = 0.f;
    if (wv == 0 && ln < ROWS) gcur = gi[grow_of(hbase, ln)];
    if (wv == 0 && ln < HPW) {
        hcur = h0[hbase + ln];
        // bootstrap: publish h(0) records, epoch 0, slot 0
        __hip_atomic_store(&rec[hbase + ln], pack_rec(hcur, 0u),
                           __ATOMIC_RELAXED, __HIP_MEMORY_SCOPE_AGENT);
    }
    __syncthreads();   // lflag init visible

    for (int t = 0; t < SEQ; ++t) {
        // ---- 1) poll+deliver: wave wv<8 owns records [wv*256, wv*256+256) ----
        if (wv < 8) {
            uint64_t* rp = rec + ((size_t)(t & 1) << 11) + (wv << 8) + (ln << 2);
            uint64_t r0, r1, r2, r3;
            const unsigned tgt = (unsigned)t;
            for (;;) {
                r0 = __hip_atomic_load(rp + 0, __ATOMIC_RELAXED, __HIP_MEMORY_SCOPE_AGENT);
                r1 = __hip_atomic_load(rp + 1, __ATOMIC_RELAXED, __HIP_MEMORY_SCOPE_AGENT);
                r2 = __hip_atomic_load(rp + 2, __ATOMIC_RELAXED, __HIP_MEMORY_SCOPE_AGENT);
                r3 = __hip_atomic_load(rp + 3, __ATOMIC_RELAXED, __HIP_MEMORY_SCOPE_AGENT);
                const bool ok = ((unsigned)r0 == tgt) && ((unsigned)r1 == tgt) &&
                                ((unsigned)r2 == tgt) && ((unsigned)r3 == tgt);
                if (__all(ok)) break;
                __builtin_amdgcn_s_sleep(1);
            }
            float4 v;
            v.x = rec_val(r0); v.y = rec_val(r1); v.z = rec_val(r2); v.w = rec_val(r3);
            const int g = (wv << 6) + ln;            // granule index
            const int p = g ^ ((g >> 3) & 7);        // bank swizzle
            *(float4*)&hl[p << 2] = v;
            __hip_atomic_store(&lflag[wv], (unsigned)(t + 1),
                               __ATOMIC_RELEASE, __HIP_MEMORY_SCOPE_WORKGROUP);
        }

        // ---- 2) gi(t+1) prefetch (latency hidden under GEMV) ----
        float gnxt = 0.f;
        if (wv == 0 && ln < ROWS && t + 1 < SEQ)
            gnxt = gi[(size_t)(t + 1) * G3 + grow_of(hbase, ln)];

        // ---- 3) wait for all 8 slices ----
        {
            const unsigned tgt = (unsigned)(t + 1);
            for (;;) {
                unsigned f = tgt;
                if (ln < 8)
                    f = __hip_atomic_load(&lflag[ln], __ATOMIC_ACQUIRE,
                                          __HIP_MEMORY_SCOPE_WORKGROUP);
                if (__all(f >= tgt)) break;
            }
        }

        // ---- 4) GEMV: 8 swizzled float4 reads, 2 rows, butterfly reduce ----
        float acc0 = 0.f, acc1 = 0.f;
#pragma unroll
        for (int k = 0; k < 8; ++k) {
            const int g = (ln << 3) + k;
            const int p = g ^ ((g >> 3) & 7);
            const float4 h4 = *(const float4*)&hl[p << 2];
            acc0 += wa[k].x * h4.x + wa[k].y * h4.y + wa[k].z * h4.z + wa[k].w * h4.w;
            acc1 += wb[k].x * h4.x + wb[k].y * h4.y + wb[k].z * h4.z + wb[k].w * h4.w;
        }
#pragma unroll
        for (int d = 1; d < 64; d <<= 1) {
            acc0 += __shfl_xor(acc0, d);
            acc1 += __shfl_xor(acc1, d);
        }
        if (ln == 0) { part[lr0] = acc0 + b0; part[lr1] = acc1 + b1; }
        __syncthreads();   // part ready; also: all GEMV reads of hl done

        // ---- 5) gates + publish h(t+1) (wave 0) ----
        if (wv == 0) {
            const float iz  = __shfl(gcur, ln + 8);   // wraps for ln>=56; unused
            const float in_ = __shfl(gcur, ln + 16);
            if (ln < HPW) {
                const float hr = part[ln], hz = part[8 + ln], hn = part[16 + ln];
                const float rg_ = sigm(gcur + hr);
                const float zg_ = sigm(iz + hz);
                const float ng_ = tanh_fast(in_ + rg_ * hn);
                const float hnew = (1.f - zg_) * ng_ + zg_ * hcur;
                hcur = hnew;
                __hip_atomic_store(&rec[((size_t)((t + 1) & 1) << 11) + hbase + ln],
                                   pack_rec(hnew, (unsigned)(t + 1)),
                                   __ATOMIC_RELAXED, __HIP_MEMORY_SCOPE_AGENT);
                if (t == SEQ - 1) hout[hbase + ln] = hnew;
            }
            gcur = gnxt;
        }
    }
}

// ---------------------------------------------------------------------------
// Kernel 3: GEMV  out[row] = act( b[row] + dot(h, w[row]) )
// ---------------------------------------------------------------------------
__global__ __launch_bounds__(256) void mlp_gemv(const float* __restrict__ h,
                                                const float* __restrict__ w,
                                                const float* __restrict__ b,
                                                float* __restrict__ out,
                                                int relu) {
    __shared__ __align__(16) float hs[HID];
    for (int i = threadIdx.x; i < HID; i += 256) hs[i] = h[i];
    __syncthreads();
    const int wv = threadIdx.x >> 6, ln = threadIdx.x & 63;
    const int row = (blockIdx.x << 2) + wv;
    const float* wp = w + (size_t)row * HID;
    float acc = 0.f;
#pragma unroll
    for (int i = 0; i < 8; ++i) {
        const int o = ((i << 6) + ln) << 2;
        const float4 w4 = *(const float4*)(wp + o);
        const float4 h4 = *(const float4*)&hs[o];
        acc += w4.x * h4.x + w4.y * h4.y + w4.z * h4.z + w4.w * h4.w;
    }
#pragma unroll
    for (int d = 1; d < 64; d <<= 1) acc += __shfl_xor(acc, d);
    if (ln == 0) {
        float v = acc + (b ? b[row] : 0.f);
        if (relu) v = fmaxf(v, 0.f);
        out[row] = v;
    }
}

// ---------------------------------------------------------------------------
extern "C" void kernel_launch(void* const* d_in, const int* in_sizes, int n_in,
                              void* d_out, int out_size, void* d_ws, size_t ws_size,
                              hipStream_t stream) {
    const float* x   = (const float*)d_in[0];
    const float* h0  = (const float*)d_in[1];
    const float* wih = (const float*)d_in[2];
    const float* whh = (const float*)d_in[3];
    const float* bih = (const float*)d_in[4];
    const float* bhh = (const float*)d_in[5];
    const float* fw1 = (const float*)d_in[6];
    const float* fb1 = (const float*)d_in[7];
    const float* fw2 = (const float*)d_in[8];
    float* out = (float*)d_out;

    char* ws = (char*)d_ws;
    uint64_t* rec = (uint64_t*)(ws + WS_REC);
    float* hbuf   = (float*)(ws + WS_H);
    float* h1buf  = (float*)(ws + WS_H1);
    float* gibuf  = (float*)(ws + WS_GI);
    // No init needed: 0xAA poison never matches an exact epoch in [0,4096],
    // and every slot-0 record is written by its owner before anyone consumes it.

    dim3 gg(SEQ / 64, G3 / 64);
    gi_gemm<<<gg, 256, 0, stream>>>(x, wih, bih, gibuf);

    gru_scan<<<NWG, TPB, 0, stream>>>(whh, bhh, gibuf, h0, rec, hbuf);

    mlp_gemv<<<HID / 4, 256, 0, stream>>>(hbuf, fw1, fb1, h1buf, 1);
    mlp_gemv<<<HID / 4, 256, 0, stream>>>(h1buf, fw2, nullptr, out, 0);
}

// Round 5
// 14000.160 us; speedup vs baseline: 2.3953x; 1.3569x over previous
//
#include <hip/hip_runtime.h>
#include <math.h>
#include <stdint.h>

// Problem sizes (fixed by the reference)
#define SEQ 4096
#define IND 2048
#define HID 2048
#define G3  (3 * HID)

// Persistent scan geometry
#define NWG  256    // one workgroup per CU
#define TPB  768    // 12 waves; waves 10,11 are also pollers
#define HPW  8      // h-indices owned per WG
#define ROWS 24     // 3 gates * 8

// Workspace layout (bytes)
#define WS_REC 0        // h records: 2 slots * 2048 * 8B = 32 KB
#define WS_H   32768    // final hidden state
#define WS_H1  45056    // MLP intermediate
#define WS_GI  65536    // gi_all: 4096*6144 floats

__device__ __forceinline__ int grow_of(int hbase, int r) {
    return ((r >> 3) << 11) + hbase + (r & 7);   // gate*2048 + hbase + idx
}
__device__ __forceinline__ float sigm(float x) { return 1.f / (1.f + __expf(-x)); }
__device__ __forceinline__ float tanh_fast(float x) {
    const float e = __expf(2.f * x);
    return 1.f - 2.f / (e + 1.f);
}
__device__ __forceinline__ uint64_t pack_rec(float v, unsigned e) {
    union { float f; unsigned u; } c; c.f = v;
    return ((uint64_t)c.u << 32) | (uint64_t)e;
}
__device__ __forceinline__ float rec_val(uint64_t r) {
    union { unsigned u; float f; } c; c.u = (unsigned)(r >> 32);
    return c.f;
}

// ---------------------------------------------------------------------------
// Kernel 1: gi_all = x @ w_ih^T + b_ih  (unchanged; ~1.2 ms)
// ---------------------------------------------------------------------------
__global__ __launch_bounds__(256) void gi_gemm(const float* __restrict__ x,
                                               const float* __restrict__ w,
                                               const float* __restrict__ bih,
                                               float* __restrict__ gi) {
    constexpr int BM = 64, BN = 64, BK = 16, PAD = 4;
    __shared__ __align__(16) float As[BK][BM + PAD];
    __shared__ __align__(16) float Bs[BK][BN + PAD];

    const int tid = threadIdx.x;
    const int m0 = blockIdx.x * BM;
    const int n0 = blockIdx.y * BN;
    const int tx = tid & 15, ty = tid >> 4;
    const int lm = tid >> 2;
    const int lk = (tid & 3) << 2;

    const float* xp = x + (size_t)(m0 + lm) * IND + lk;
    const float* wp = w + (size_t)(n0 + lm) * IND + lk;

    float c[4][4] = {};

    for (int k0 = 0; k0 < IND; k0 += BK) {
        const float4 av = *(const float4*)(xp + k0);
        const float4 bv = *(const float4*)(wp + k0);
        __syncthreads();
        As[lk + 0][lm] = av.x; As[lk + 1][lm] = av.y;
        As[lk + 2][lm] = av.z; As[lk + 3][lm] = av.w;
        Bs[lk + 0][lm] = bv.x; Bs[lk + 1][lm] = bv.y;
        Bs[lk + 2][lm] = bv.z; Bs[lk + 3][lm] = bv.w;
        __syncthreads();
#pragma unroll
        for (int k = 0; k < BK; ++k) {
            const float4 a  = *(const float4*)&As[k][ty << 2];
            const float4 bb = *(const float4*)&Bs[k][tx << 2];
            const float ar[4] = {a.x, a.y, a.z, a.w};
            const float br[4] = {bb.x, bb.y, bb.z, bb.w};
#pragma unroll
            for (int i = 0; i < 4; ++i)
#pragma unroll
                for (int j = 0; j < 4; ++j) c[i][j] += ar[i] * br[j];
        }
    }

    const int nb = n0 + (tx << 2);
    const float4 bias = *(const float4*)(bih + nb);
    const float bres[4] = {bias.x, bias.y, bias.z, bias.w};
#pragma unroll
    for (int i = 0; i < 4; ++i) {
        const int m = m0 + (ty << 2) + i;
        float4 o;
        o.x = c[i][0] + bres[0]; o.y = c[i][1] + bres[1];
        o.z = c[i][2] + bres[2]; o.w = c[i][3] + bres[3];
        *(float4*)(gi + (size_t)m * G3 + nb) = o;
    }
}

// ---------------------------------------------------------------------------
// Kernel 2: persistent GRU scan — fused 8B records, 2 poller waves.
//   waves 10,11: poll 1024 records each (16 coalesced 8B agent loads/lane,
//   stride 64 records -> each load instr covers 512 contiguous bytes),
//   deposit swizzled into LDS, raise one LDS flag each.
//   all 12 waves: GEMV rows {2wv,2wv+1} from register weights.
//   wave 0: gates + publish 8 fused records (1 agent store each, no fence).
// ---------------------------------------------------------------------------
__global__ __launch_bounds__(TPB, 3) void gru_scan(const float* __restrict__ whh,
                                                   const float* __restrict__ bhh,
                                                   const float* __restrict__ gi,
                                                   const float* __restrict__ h0,
                                                   uint64_t* rec,
                                                   float* __restrict__ hout) {
    __shared__ __align__(16) float hl[HID];   // swizzled granules
    __shared__ float part[ROWS];
    __shared__ unsigned lflag[2];

    const int tid = threadIdx.x;
    const int wg  = blockIdx.x;
    const int hbase = wg * HPW;
    const int wv = tid >> 6, ln = tid & 63;

    if (tid < 2) lflag[tid] = 0;

    // ---- weights for rows {2wv, 2wv+1}, lane's 8 column-granules ----
    const int lr0 = 2 * wv, lr1 = lr0 + 1;
    const int grow0 = grow_of(hbase, lr0);
    const int grow1 = grow_of(hbase, lr1);
    const float* w0p = whh + (size_t)grow0 * HID;
    const float* w1p = whh + (size_t)grow1 * HID;
    float4 wa[8], wb[8];
#pragma unroll
    for (int k = 0; k < 8; ++k) {
        wa[k] = *(const float4*)(w0p + (((ln << 3) + k) << 2));
        wb[k] = *(const float4*)(w1p + (((ln << 3) + k) << 2));
    }
    const float b0 = bhh[grow0], b1 = bhh[grow1];

    // ---- wave 0 state: gi prefetch (lanes<24), h_prev regs (lanes<8) ----
    float gcur = 0.f, hcur = 0.f;
    if (wv == 0 && ln < ROWS) gcur = gi[grow_of(hbase, ln)];
    if (wv == 0 && ln < HPW) {
        hcur = h0[hbase + ln];
        __hip_atomic_store(&rec[hbase + ln], pack_rec(hcur, 0u),
                           __ATOMIC_RELAXED, __HIP_MEMORY_SCOPE_AGENT);
    }
    __syncthreads();   // lflag init visible

    for (int t = 0; t < SEQ; ++t) {
        // ---- pollers: detect + deposit + flag ----
        if (wv >= 10) {
            const int p = wv - 10;
            uint64_t* rp = rec + ((size_t)(t & 1) << 11) + (p << 10) + ln;
            const unsigned tgt = (unsigned)t;
            uint64_t r[16];
            for (;;) {
                bool ok = true;
#pragma unroll
                for (int k = 0; k < 16; ++k)
                    r[k] = __hip_atomic_load(rp + (k << 6), __ATOMIC_RELAXED,
                                             __HIP_MEMORY_SCOPE_AGENT);
#pragma unroll
                for (int k = 0; k < 16; ++k) ok &= ((unsigned)r[k] == tgt);
                if (__all(ok)) break;
            }
#pragma unroll
            for (int k = 0; k < 16; ++k) {
                const int i = (p << 10) + (k << 6) + ln;      // h index
                const int g = i >> 2;
                const int pos = g ^ ((g >> 3) & 7);
                hl[(pos << 2) + (i & 3)] = rec_val(r[k]);
            }
            __hip_atomic_store(&lflag[p], tgt + 1,
                               __ATOMIC_RELEASE, __HIP_MEMORY_SCOPE_WORKGROUP);
        }

        // ---- gi(t+1) prefetch (latency hidden under spin+GEMV) ----
        float gnxt = 0.f;
        if (wv == 0 && ln < ROWS && t + 1 < SEQ)
            gnxt = gi[(size_t)(t + 1) * G3 + grow_of(hbase, ln)];

        // ---- wait for both deposits ----
        {
            const unsigned tgt = (unsigned)(t + 1);
            for (;;) {
                const unsigned f0 = __hip_atomic_load(&lflag[0], __ATOMIC_ACQUIRE,
                                                      __HIP_MEMORY_SCOPE_WORKGROUP);
                const unsigned f1 = __hip_atomic_load(&lflag[1], __ATOMIC_ACQUIRE,
                                                      __HIP_MEMORY_SCOPE_WORKGROUP);
                if (f0 >= tgt && f1 >= tgt) break;
                __builtin_amdgcn_s_sleep(1);
            }
        }

        // ---- GEMV: 8 swizzled float4 reads, 2 rows, butterfly reduce ----
        float acc0 = 0.f, acc1 = 0.f;
#pragma unroll
        for (int k = 0; k < 8; ++k) {
            const int g = (ln << 3) + k;
            const int pos = g ^ (ln & 7);
            const float4 h4 = *(const float4*)&hl[pos << 2];
            acc0 += wa[k].x * h4.x + wa[k].y * h4.y + wa[k].z * h4.z + wa[k].w * h4.w;
            acc1 += wb[k].x * h4.x + wb[k].y * h4.y + wb[k].z * h4.z + wb[k].w * h4.w;
        }
#pragma unroll
        for (int d = 1; d < 64; d <<= 1) {
            acc0 += __shfl_xor(acc0, d);
            acc1 += __shfl_xor(acc1, d);
        }
        if (ln == 0) { part[lr0] = acc0 + b0; part[lr1] = acc1 + b1; }
        __syncthreads();   // part ready; all GEMV reads of hl done

        // ---- gates + publish h(t+1) (wave 0) ----
        if (wv == 0) {
            const float iz  = __shfl(gcur, ln + 8);
            const float in_ = __shfl(gcur, ln + 16);
            if (ln < HPW) {
                const float hr = part[ln], hz = part[8 + ln], hn = part[16 + ln];
                const float rg_ = sigm(gcur + hr);
                const float zg_ = sigm(iz + hz);
                const float ng_ = tanh_fast(in_ + rg_ * hn);
                const float hnew = (1.f - zg_) * ng_ + zg_ * hcur;
                hcur = hnew;
                __hip_atomic_store(&rec[((size_t)((t + 1) & 1) << 11) + hbase + ln],
                                   pack_rec(hnew, (unsigned)(t + 1)),
                                   __ATOMIC_RELAXED, __HIP_MEMORY_SCOPE_AGENT);
                if (t == SEQ - 1) hout[hbase + ln] = hnew;
            }
            gcur = gnxt;
        }
    }
}

// ---------------------------------------------------------------------------
// Kernel 3: GEMV  out[row] = act( b[row] + dot(h, w[row]) )
// ---------------------------------------------------------------------------
__global__ __launch_bounds__(256) void mlp_gemv(const float* __restrict__ h,
                                                const float* __restrict__ w,
                                                const float* __restrict__ b,
                                                float* __restrict__ out,
                                                int relu) {
    __shared__ __align__(16) float hs[HID];
    for (int i = threadIdx.x; i < HID; i += 256) hs[i] = h[i];
    __syncthreads();
    const int wv = threadIdx.x >> 6, ln = threadIdx.x & 63;
    const int row = (blockIdx.x << 2) + wv;
    const float* wp = w + (size_t)row * HID;
    float acc = 0.f;
#pragma unroll
    for (int i = 0; i < 8; ++i) {
        const int o = ((i << 6) + ln) << 2;
        const float4 w4 = *(const float4*)(wp + o);
        const float4 h4 = *(const float4*)&hs[o];
        acc += w4.x * h4.x + w4.y * h4.y + w4.z * h4.z + w4.w * h4.w;
    }
#pragma unroll
    for (int d = 1; d < 64; d <<= 1) acc += __shfl_xor(acc, d);
    if (ln == 0) {
        float v = acc + (b ? b[row] : 0.f);
        if (relu) v = fmaxf(v, 0.f);
        out[row] = v;
    }
}

// ---------------------------------------------------------------------------
extern "C" void kernel_launch(void* const* d_in, const int* in_sizes, int n_in,
                              void* d_out, int out_size, void* d_ws, size_t ws_size,
                              hipStream_t stream) {
    const float* x   = (const float*)d_in[0];
    const float* h0  = (const float*)d_in[1];
    const float* wih = (const float*)d_in[2];
    const float* whh = (const float*)d_in[3];
    const float* bih = (const float*)d_in[4];
    const float* bhh = (const float*)d_in[5];
    const float* fw1 = (const float*)d_in[6];
    const float* fb1 = (const float*)d_in[7];
    const float* fw2 = (const float*)d_in[8];
    float* out = (float*)d_out;

    char* ws = (char*)d_ws;
    uint64_t* rec = (uint64_t*)(ws + WS_REC);
    float* hbuf   = (float*)(ws + WS_H);
    float* h1buf  = (float*)(ws + WS_H1);
    float* gibuf  = (float*)(ws + WS_GI);
    // No ws init needed: 0xAA poison never equals a live epoch, and slot-0
    // records are bootstrap-published before anyone can consume them.

    dim3 gg(SEQ / 64, G3 / 64);
    gi_gemm<<<gg, 256, 0, stream>>>(x, wih, bih, gibuf);

    gru_scan<<<NWG, TPB, 0, stream>>>(whh, bhh, gibuf, h0, rec, hbuf);

    mlp_gemv<<<HID / 4, 256, 0, stream>>>(hbuf, fw1, fb1, h1buf, 1);
    mlp_gemv<<<HID / 4, 256, 0, stream>>>(h1buf, fw2, nullptr, out, 0);
}